// Round 1
// baseline (185.730 us; speedup 1.0000x reference)
//
#include <hip/hip_runtime.h>

// MatrixFactorization: out[n] = dot(concat(Wdow[dow[n]],Wtim[tim[n]],Wmon[mon[n]],Wday[day[n]]),
//                                   Witem[dest[n]])
// N = 1,048,576; 128-dim item rows (512B); small tables total 2368 floats (9.25KB -> LDS).
//
// Layout: half-wave (32 lanes) per sample. Lane sub in [0,32):
//   item float4  = Witem[dest*128 + sub*4 ..]          (32 x 16B = coalesced 512B row)
//   user float4  = LDS table[t = sub>>3][idx*32 + (sub&7)*4 ..]
// 5-step __shfl_xor reduce (masks <32 stay within the half-wave), lane sub==0 writes out.

constexpr int NDIM = 32;
constexpr int SZ_DOW = 7 * NDIM;     // 224
constexpr int SZ_TIM = 24 * NDIM;    // 768
constexpr int SZ_MON = 12 * NDIM;    // 384
constexpr int SZ_DAY = 31 * NDIM;    // 992
constexpr int B_DOW = 0;
constexpr int B_TIM = B_DOW + SZ_DOW;   // 224  (multiple of 32 -> 16B-aligned float4 rows)
constexpr int B_MON = B_TIM + SZ_TIM;   // 992
constexpr int B_DAY = B_MON + SZ_MON;   // 1376
constexpr int TAB_TOT = B_DAY + SZ_DAY; // 2368 floats = 9472 B LDS

__global__ __launch_bounds__(256, 8)
void mf_dot_kernel(const int* __restrict__ dow, const int* __restrict__ tim,
                   const int* __restrict__ mon, const int* __restrict__ day,
                   const int* __restrict__ dest,
                   const float* __restrict__ Wdow, const float* __restrict__ Wtim,
                   const float* __restrict__ Wmon, const float* __restrict__ Wday,
                   const float* __restrict__ Witem,
                   float* __restrict__ out, int n_samples)
{
    __shared__ float tab[TAB_TOT];

    const int tid = threadIdx.x;
    // Stage small embedding tables into LDS (once per block).
    for (int i = tid; i < SZ_DOW; i += 256) tab[B_DOW + i] = Wdow[i];
    for (int i = tid; i < SZ_TIM; i += 256) tab[B_TIM + i] = Wtim[i];
    for (int i = tid; i < SZ_MON; i += 256) tab[B_MON + i] = Wmon[i];
    for (int i = tid; i < SZ_DAY; i += 256) tab[B_DAY + i] = Wday[i];
    __syncthreads();

    const int lane = tid & 63;
    const int sub  = lane & 31;   // lane within half-wave (one sample)
    const int wave = tid >> 6;    // wave within block: 0..3
    const int half = lane >> 5;   // which of the 2 samples this wave handles
    const int t    = sub >> 3;    // table id 0..3
    const int dofs = (sub & 7) * 4; // float offset within the 32-dim table row

    const int* idxp  = (t == 0) ? dow   : (t == 1) ? tim   : (t == 2) ? mon   : day;
    const int  tbase = (t == 0) ? B_DOW : (t == 1) ? B_TIM : (t == 2) ? B_MON : B_DAY;

    // grid-stride over samples; 8 samples per block per iteration
    const int  samp_per_blk = (blockDim.x >> 6) * 2;      // 8
    long n      = (long)blockIdx.x * samp_per_blk + wave * 2 + half;
    const long stride = (long)gridDim.x * samp_per_blk;

    for (; n < n_samples; n += stride) {
        const int idx = idxp[n];          // 4 distinct addrs per half-wave (broadcast within group of 8)
        const int ds  = dest[n];          // same addr across half-wave -> broadcast

        const float4 u  = *reinterpret_cast<const float4*>(&tab[tbase + idx * NDIM + dofs]);
        const float4 it = *reinterpret_cast<const float4*>(&Witem[(long)ds * 128 + sub * 4]);

        float p = u.x * it.x + u.y * it.y + u.z * it.z + u.w * it.w;
        // reduce across the 32-lane half (xor masks < 32 stay within the half)
        p += __shfl_xor(p, 16);
        p += __shfl_xor(p, 8);
        p += __shfl_xor(p, 4);
        p += __shfl_xor(p, 2);
        p += __shfl_xor(p, 1);

        if (sub == 0) out[n] = p;
    }
}

extern "C" void kernel_launch(void* const* d_in, const int* in_sizes, int n_in,
                              void* d_out, int out_size, void* d_ws, size_t ws_size,
                              hipStream_t stream)
{
    const int*   dow   = (const int*)d_in[0];
    const int*   tim   = (const int*)d_in[1];
    const int*   mon   = (const int*)d_in[2];
    const int*   day   = (const int*)d_in[3];
    const int*   dest  = (const int*)d_in[4];
    const float* Wdow  = (const float*)d_in[5];
    const float* Wtim  = (const float*)d_in[6];
    const float* Wmon  = (const float*)d_in[7];
    const float* Wday  = (const float*)d_in[8];
    const float* Witem = (const float*)d_in[9];
    float* out = (float*)d_out;

    const int n = in_sizes[0];  // 1048576

    // 2048 blocks x 4 waves = 8192 waves -> full 32-waves/CU occupancy on 256 CUs,
    // maximal latency hiding for the L3-bound item gathers.
    dim3 grid(2048), block(256);
    hipLaunchKernelGGL(mf_dot_kernel, grid, block, 0, stream,
                       dow, tim, mon, day, dest,
                       Wdow, Wtim, Wmon, Wday, Witem, out, n);
}